// Round 1
// baseline (23467.662 us; speedup 1.0000x reference)
//
#include <hip/hip_runtime.h>
#include <stdint.h>

// MultiRateLSTM on MI355X.
// Persistent kernel: 16 WGs x 256 threads. WG g owns hidden units [16g,16g+16).
// Wave w (4/WG) owns units 16g+4w..+3, all 4 gates (i,f,g,o) -> 16 MFMA N-cols.
// All weights pre-converted to f16 MFMA B-fragments held in VGPRs (~152/lane).
// Per step: stage x (overlaps spin) -> wait per-WG flags -> load h (8KB, f16,
// double-buffered in ws) -> LDS -> K/32 MFMAs (K=512/384/320 by branch) ->
// intra-wave shfl gather of i/f/g/o -> c,h update (c fp32 in regs) ->
// store d_out fp32 + h f16 broadcast -> release flag.

typedef _Float16 half8 __attribute__((ext_vector_type(8)));
typedef float floatx4 __attribute__((ext_vector_type(4)));

#define T_STEPS 8192
#define NWG 16

__device__ __forceinline__ float fsig(float x) {
    return __builtin_amdgcn_rcpf(1.0f + __expf(-x));
}
__device__ __forceinline__ float ftanh(float x) {
    // 1 - 2/(e^{2x}+1); saturates correctly at +-inf
    return 1.0f - 2.0f * __builtin_amdgcn_rcpf(1.0f + __expf(2.0f * x));
}

__device__ __forceinline__ half8 ld8w(const float* p) {
    floatx4 a = *(const floatx4*)p;
    floatx4 b = *(const floatx4*)(p + 4);
    half8 h;
    h[0] = (_Float16)a[0]; h[1] = (_Float16)a[1]; h[2] = (_Float16)a[2]; h[3] = (_Float16)a[3];
    h[4] = (_Float16)b[0]; h[5] = (_Float16)b[1]; h[6] = (_Float16)b[2]; h[7] = (_Float16)b[3];
    return h;
}

// ws layout: [0,2048) flags (int, stride 128B), [4096,12288) h buf0 f16[16][256],
// [12288,20480) h buf1. ws is re-poisoned 0xAA before every timed launch -> init kernel.
__global__ void init_ws_kernel(uint32_t* ws) {
    for (int i = threadIdx.x; i < 5120; i += 256) ws[i] = 0;
}

__global__ __launch_bounds__(256, 1) void lstm_kernel(
    const float* __restrict__ x0, const float* __restrict__ x1, const float* __restrict__ x2,
    const float* __restrict__ Wih_a, const float* __restrict__ Whh_a,
    const float* __restrict__ bih_a, const float* __restrict__ bhh_a,
    const float* __restrict__ Wih_b, const float* __restrict__ Whh_b,
    const float* __restrict__ bih_b, const float* __restrict__ bhh_b,
    const float* __restrict__ Wih_c, const float* __restrict__ Whh_c,
    const float* __restrict__ bih_c, const float* __restrict__ bhh_c,
    float* __restrict__ out, uint8_t* __restrict__ ws)
{
    const int tid = threadIdx.x;
    const int g   = blockIdx.x;      // 0..15
    const int w   = tid >> 6;        // wave 0..3
    const int l   = tid & 63;
    const int n   = l & 15;          // MFMA col within wave tile
    const int mg  = l >> 4;          // quad (batch group)
    const int up  = n & 3;           // unit-within-wave
    const int gt  = n >> 2;          // gate type: 0=i 1=f 2=g 3=o (torch order)
    const int unit = g * 16 + w * 4 + up;
    const int R    = gt * 256 + unit;   // global weight row

    int* flags = (int*)ws;
    _Float16* buf0 = (_Float16*)(ws + 4096);
    _Float16* buf1 = (_Float16*)(ws + 4096 + 8192);

    // LDS staging of [x | h], padded row stride 520 halfs (1040B: 16B-aligned,
    // bank shift 4 -> only 2-way conflict on frag reads, which is free).
    __shared__ _Float16 XH[16][520];

    // ---- preload weights as B-fragments into registers ----
    // B-frag (16x16x32 f16): lane l supplies B[k=(l>>4)*8+j][ncol=l&15] = W[R(n)][k]
    half8 wfa[16], wfb[12], wfc[10];
    {
        const int ko = mg * 8;
        #pragma unroll
        for (int kt = 0; kt < 8; ++kt) wfa[kt]     = ld8w(Wih_a + (size_t)R * 256 + kt * 32 + ko);
        #pragma unroll
        for (int kt = 0; kt < 8; ++kt) wfa[8 + kt] = ld8w(Whh_a + (size_t)R * 256 + kt * 32 + ko);
        #pragma unroll
        for (int kt = 0; kt < 4; ++kt) wfb[kt]     = ld8w(Wih_b + (size_t)R * 128 + kt * 32 + ko);
        #pragma unroll
        for (int kt = 0; kt < 8; ++kt) wfb[4 + kt] = ld8w(Whh_b + (size_t)R * 256 + kt * 32 + ko);
        #pragma unroll
        for (int kt = 0; kt < 2; ++kt) wfc[kt]     = ld8w(Wih_c + (size_t)R * 64  + kt * 32 + ko);
        #pragma unroll
        for (int kt = 0; kt < 8; ++kt) wfc[2 + kt] = ld8w(Whh_c + (size_t)R * 256 + kt * 32 + ko);
    }
    const float ba = bih_a[R] + bhh_a[R];
    const float bb = bih_b[R] + bhh_b[R];
    const float bc = bih_c[R] + bhh_c[R];

    float cst[4] = {0.f, 0.f, 0.f, 0.f};   // c-state, 4 batches (replicated x4 lanes/group)

    for (int t = 0; t < T_STEPS; ++t) {
        // join prev iter: all waves done with LDS reads + global h/out stores
        __syncthreads();
        // announce completion of step t-1 (release: drains + wbl2 so remote XCDs see h)
        if (tid == 0)
            __hip_atomic_store(&flags[g * 32], t, __ATOMIC_RELEASE, __HIP_MEMORY_SCOPE_AGENT);

        const int br = ((t & 3) == 0) ? 0 : (((t & 1) == 0) ? 1 : 2);
        const int kx = (br == 0) ? 256 : ((br == 1) ? 128 : 64);

        // ---- stage x (independent of h; overlaps other WGs' flag latency) ----
        if (tid < 128) {
            const int m = tid >> 3, cg = (tid & 7) * 8;
            *(half8*)&XH[m][cg] = ld8w(x0 + (size_t)t * 1024 + m * 64 + cg);
        } else if (br < 2) {
            const int tt = tid - 128;
            const int m = tt >> 3, cg = (tt & 7) * 8;
            *(half8*)&XH[m][64 + cg] = ld8w(x1 + (size_t)(t >> 1) * 1024 + m * 64 + cg);
        }
        if (br == 0) {
            const int m = tid >> 4, cg = (tid & 15) * 8;
            *(half8*)&XH[m][128 + cg] = ld8w(x2 + (size_t)(t >> 2) * 2048 + m * 128 + cg);
        }

        // ---- wait for all WGs to have finished step t-1 ----
        if (w == 0) {
            if (l < NWG) {
                while (__hip_atomic_load(&flags[l * 32], __ATOMIC_RELAXED,
                                         __HIP_MEMORY_SCOPE_AGENT) < t) { }
            }
            __builtin_amdgcn_fence(__ATOMIC_ACQUIRE, "agent");
        }
        __syncthreads();

        // ---- stage h(t-1) from buf[(t-1)&1] ----
        {
            const _Float16* hb = ((t & 1) == 0) ? buf1 : buf0;
            const int m = tid >> 4, cg = (tid & 15) * 16;
            uint4 q0 = *(const uint4*)(hb + m * 256 + cg);
            uint4 q1 = *(const uint4*)(hb + m * 256 + cg + 8);
            *(uint4*)&XH[m][kx + cg]     = q0;
            *(uint4*)&XH[m][kx + cg + 8] = q1;
        }
        __syncthreads();

        // ---- gates = [x|h] @ W^T : A-frag lane l = XH[m=l&15][kt*32 + (l>>4)*8 + j] ----
        floatx4 acc = {0.f, 0.f, 0.f, 0.f};
        {
            const int ao = mg * 8;
            if (br == 0) {
                #pragma unroll
                for (int kt = 0; kt < 16; ++kt)
                    acc = __builtin_amdgcn_mfma_f32_16x16x32_f16(
                        *(const half8*)&XH[n][kt * 32 + ao], wfa[kt], acc, 0, 0, 0);
            } else if (br == 1) {
                #pragma unroll
                for (int kt = 0; kt < 12; ++kt)
                    acc = __builtin_amdgcn_mfma_f32_16x16x32_f16(
                        *(const half8*)&XH[n][kt * 32 + ao], wfb[kt], acc, 0, 0, 0);
            } else {
                #pragma unroll
                for (int kt = 0; kt < 10; ++kt)
                    acc = __builtin_amdgcn_mfma_f32_16x16x32_f16(
                        *(const half8*)&XH[n][kt * 32 + ao], wfc[kt], acc, 0, 0, 0);
            }
        }

        // ---- elementwise: gather i,f,g,o across the 4 lanes of the group ----
        const float bsel = (br == 0) ? ba : ((br == 1) ? bb : bc);
        float h2v[4];
        const int b0 = l & ~12;   // lane holding gate i of this (unit, quad)
        #pragma unroll
        for (int r = 0; r < 4; ++r) {
            const float gv = acc[r] + bsel;   // each lane adds its own gate's bias
            const float vi = __shfl(gv, b0,      64);
            const float vf = __shfl(gv, b0 + 4,  64);
            const float vg = __shfl(gv, b0 + 8,  64);
            const float vo = __shfl(gv, b0 + 12, 64);
            const float c2 = fsig(vf) * cst[r] + fsig(vi) * ftanh(vg);
            cst[r] = c2;                       // replicated consistently across group
            h2v[r] = fsig(vo) * ftanh(c2);
        }

        // ---- store output ys[t] (fp32) ----
        if ((l & 12) == 0) {   // one lane per (unit, quad): n = up
            float* op = out + (size_t)t * 4096 + (size_t)(mg * 4) * 256 + unit;
            #pragma unroll
            for (int r = 0; r < 4; ++r) op[r * 256] = h2v[r];
        }

        // ---- broadcast h(t) as f16 into buf[t&1]: pack 4 units -> 8B store ----
        {
            _Float16* hw = (t & 1) ? buf1 : buf0;
            const int s0 = l & ~15;
            #pragma unroll
            for (int r = 0; r < 4; ++r) {
                const unsigned hv =
                    (unsigned)__builtin_bit_cast(unsigned short, (_Float16)h2v[r]);
                const unsigned v0 = (unsigned)__shfl((int)hv, s0,     64);
                const unsigned v1 = (unsigned)__shfl((int)hv, s0 + 1, 64);
                const unsigned v2 = (unsigned)__shfl((int)hv, s0 + 2, 64);
                const unsigned v3 = (unsigned)__shfl((int)hv, s0 + 3, 64);
                if (n == 0) {
                    const unsigned long long pk =
                          (unsigned long long)(v0 & 0xffffu)
                        | ((unsigned long long)(v1 & 0xffffu) << 16)
                        | ((unsigned long long)(v2 & 0xffffu) << 32)
                        | ((unsigned long long)(v3 & 0xffffu) << 48);
                    *(unsigned long long*)(hw + (size_t)(mg * 4 + r) * 256 + g * 16 + w * 4) = pk;
                }
            }
        }
    }
}

extern "C" void kernel_launch(void* const* d_in, const int* in_sizes, int n_in,
                              void* d_out, int out_size, void* d_ws, size_t ws_size,
                              hipStream_t stream) {
    (void)in_sizes; (void)n_in; (void)out_size; (void)ws_size;
    hipLaunchKernelGGL(init_ws_kernel, dim3(1), dim3(256), 0, stream, (uint32_t*)d_ws);
    hipLaunchKernelGGL(lstm_kernel, dim3(NWG), dim3(256), 0, stream,
        (const float*)d_in[0], (const float*)d_in[1], (const float*)d_in[2],
        (const float*)d_in[3], (const float*)d_in[4], (const float*)d_in[5], (const float*)d_in[6],
        (const float*)d_in[7], (const float*)d_in[8], (const float*)d_in[9], (const float*)d_in[10],
        (const float*)d_in[11], (const float*)d_in[12], (const float*)d_in[13], (const float*)d_in[14],
        (float*)d_out, (uint8_t*)d_ws);
}

// Round 2
// 19781.516 us; speedup vs baseline: 1.1863x; 1.1863x over previous
//
#include <hip/hip_runtime.h>
#include <stdint.h>

// MultiRateLSTM on MI355X — persistent 16-WG kernel, fence-free h exchange.
//
// 16 WGs x 256 threads. WG g owns hidden units [16g,16g+16). Wave w owns units
// 16g+4w..+3 x all 4 gates (16 MFMA cols). Weights live in VGPRs as f16 MFMA
// B-fragments (~152 regs/lane). Per step:
//   stage x -> LDS (overlaps h wait)
//   poll h(t-1) chunks (self-tagged, sc1 loads from coherence point) -> LDS
//   MFMA (2 accumulators) -> gate nonlinearities -> shfl gather -> c,h update
//   publish h(t) as {f16 h[2], u32 tag} chunks via sc1 stores (no fence!)
//   store ys[t] fp32
// Tags are unique per step, so no flag arrays, no init kernel, no L2
// writeback/invalidate (R0's buffer_wbl2/buffer_inv per step was the 2.86us
// critical path). 8B-aligned tag+data pairs rely on 8B single-copy atomicity.

typedef _Float16 half8 __attribute__((ext_vector_type(8)));
typedef float floatx4 __attribute__((ext_vector_type(4)));
typedef unsigned int u32x4 __attribute__((ext_vector_type(4)));

#define T_STEPS 8192
#define NWG 16

__device__ __forceinline__ float fsig(float x) {
    return __builtin_amdgcn_rcpf(1.0f + __expf(-x));
}
__device__ __forceinline__ float ftanh(float x) {
    return 1.0f - 2.0f * __builtin_amdgcn_rcpf(1.0f + __expf(2.0f * x));
}

__device__ __forceinline__ half8 ld8w(const float* p) {
    floatx4 a = *(const floatx4*)p;
    floatx4 b = *(const floatx4*)(p + 4);
    half8 h;
    h[0] = (_Float16)a[0]; h[1] = (_Float16)a[1]; h[2] = (_Float16)a[2]; h[3] = (_Float16)a[3];
    h[4] = (_Float16)b[0]; h[5] = (_Float16)b[1]; h[6] = (_Float16)b[2]; h[7] = (_Float16)b[3];
    return h;
}

// 64B agent-coherent load (bypasses non-coherent per-XCD L2), one vmcnt drain.
__device__ __forceinline__ void ld64_sc1(const void* p, u32x4& a, u32x4& b, u32x4& c, u32x4& d) {
    asm volatile(
        "global_load_dwordx4 %0, %4, off sc1\n\t"
        "global_load_dwordx4 %1, %4, off offset:16 sc1\n\t"
        "global_load_dwordx4 %2, %4, off offset:32 sc1\n\t"
        "global_load_dwordx4 %3, %4, off offset:48 sc1\n\t"
        "s_waitcnt vmcnt(0)"
        : "=&v"(a), "=&v"(b), "=&v"(c), "=&v"(d)
        : "v"(p)
        : "memory");
}
__device__ __forceinline__ void st16_sc1(void* p, u32x4 v) {
    asm volatile("global_store_dwordx4 %0, %1, off sc1" :: "v"(p), "v"(v) : "memory");
}

// ws ring: slot s (s = t & smask) at ws + s*16384:
//   [16 rows][128 chunks x 8B]  chunk c = { f16 h[2c], f16 h[2c+1], u32 tag=t }
__global__ __launch_bounds__(256, 1) void lstm_kernel(
    const float* __restrict__ x0, const float* __restrict__ x1, const float* __restrict__ x2,
    const float* __restrict__ Wih_a, const float* __restrict__ Whh_a,
    const float* __restrict__ bih_a, const float* __restrict__ bhh_a,
    const float* __restrict__ Wih_b, const float* __restrict__ Whh_b,
    const float* __restrict__ bih_b, const float* __restrict__ bhh_b,
    const float* __restrict__ Wih_c, const float* __restrict__ Whh_c,
    const float* __restrict__ bih_c, const float* __restrict__ bhh_c,
    float* __restrict__ out, uint8_t* __restrict__ ws, int smask)
{
    const int tid = threadIdx.x;
    const int g   = blockIdx.x;      // 0..15
    const int w   = tid >> 6;        // wave 0..3
    const int l   = tid & 63;
    const int n   = l & 15;          // MFMA col (weights) / M row (activations)
    const int mg  = l >> 4;          // quad
    const int up  = n & 3;           // unit-within-wave
    const int gt  = n >> 2;          // gate: 0=i 1=f 2=g 3=o
    const int unit = g * 16 + w * 4 + up;
    const int R    = gt * 256 + unit;

    uint8_t* hring = ws;

    // LDS [x | h], row stride 520 halfs (1040B, 16B-aligned; bank shift 4 ->
    // only free 2-way conflicts on frag reads).
    __shared__ _Float16 XH[16][520];

    // ---- weights -> registers as B-fragments ----
    half8 wfa[16], wfb[12], wfc[10];
    {
        const int ko = mg * 8;
        #pragma unroll
        for (int kt = 0; kt < 8; ++kt) wfa[kt]     = ld8w(Wih_a + (size_t)R * 256 + kt * 32 + ko);
        #pragma unroll
        for (int kt = 0; kt < 8; ++kt) wfa[8 + kt] = ld8w(Whh_a + (size_t)R * 256 + kt * 32 + ko);
        #pragma unroll
        for (int kt = 0; kt < 4; ++kt) wfb[kt]     = ld8w(Wih_b + (size_t)R * 128 + kt * 32 + ko);
        #pragma unroll
        for (int kt = 0; kt < 8; ++kt) wfb[4 + kt] = ld8w(Whh_b + (size_t)R * 256 + kt * 32 + ko);
        #pragma unroll
        for (int kt = 0; kt < 2; ++kt) wfc[kt]     = ld8w(Wih_c + (size_t)R * 64  + kt * 32 + ko);
        #pragma unroll
        for (int kt = 0; kt < 8; ++kt) wfc[2 + kt] = ld8w(Whh_c + (size_t)R * 256 + kt * 32 + ko);
    }
    const float ba = bih_a[R] + bhh_a[R];
    const float bb = bih_b[R] + bhh_b[R];
    const float bc = bih_c[R] + bhh_c[R];

    float cst[4] = {0.f, 0.f, 0.f, 0.f};

    for (int t = 0; t < T_STEPS; ++t) {
        __syncthreads();   // prev step's LDS reads done before overwrite

        const int br = ((t & 3) == 0) ? 0 : (((t & 1) == 0) ? 1 : 2);
        const int kx = (br == 0) ? 256 : ((br == 1) ? 128 : 64);

        // ---- stage x (no h dependency; overlaps other WGs' publish latency) ----
        if (tid < 128) {
            const int m = tid >> 3, cg = (tid & 7) * 8;
            *(half8*)&XH[m][cg] = ld8w(x0 + (size_t)t * 1024 + m * 64 + cg);
        } else if (br < 2) {
            const int tt = tid - 128;
            const int m = tt >> 3, cg = (tt & 7) * 8;
            *(half8*)&XH[m][64 + cg] = ld8w(x1 + (size_t)(t >> 1) * 1024 + m * 64 + cg);
        }
        if (br == 0) {
            const int m = tid >> 4, cg = (tid & 15) * 8;
            *(half8*)&XH[m][128 + cg] = ld8w(x2 + (size_t)(t >> 2) * 2048 + m * 128 + cg);
        }

        // ---- h(t-1): poll self-tagged chunks, one round trip, no fences ----
        {
            const int row = tid >> 4, u = tid & 15;
            _Float16* dst = &XH[row][kx + u * 16];
            if (t == 0) {
                *(u32x4*)dst       = (u32x4)0u;
                *(u32x4*)(dst + 8) = (u32x4)0u;
            } else {
                const uint32_t want = (uint32_t)(t - 1);
                const uint8_t* src = hring + (size_t)((t - 1) & smask) * 16384
                                   + (size_t)row * 1024 + (size_t)u * 64;
                u32x4 a, b, c, d;
                for (;;) {
                    ld64_sc1(src, a, b, c, d);
                    if (a[1] == want && a[3] == want && b[1] == want && b[3] == want &&
                        c[1] == want && c[3] == want && d[1] == want && d[3] == want)
                        break;
                }
                u32x4 lo = {a[0], a[2], b[0], b[2]};
                u32x4 hi = {c[0], c[2], d[0], d[2]};
                *(u32x4*)dst       = lo;
                *(u32x4*)(dst + 8) = hi;
            }
        }
        __syncthreads();

        // ---- gates = [x|h] @ W^T, two accumulators to halve MFMA dep chain ----
        floatx4 ac0 = {0.f, 0.f, 0.f, 0.f}, ac1 = {0.f, 0.f, 0.f, 0.f};
        {
            const int ao = mg * 8;
            if (br == 0) {
                #pragma unroll
                for (int kt = 0; kt < 16; kt += 2) {
                    ac0 = __builtin_amdgcn_mfma_f32_16x16x32_f16(
                        *(const half8*)&XH[n][kt * 32 + ao], wfa[kt], ac0, 0, 0, 0);
                    ac1 = __builtin_amdgcn_mfma_f32_16x16x32_f16(
                        *(const half8*)&XH[n][(kt + 1) * 32 + ao], wfa[kt + 1], ac1, 0, 0, 0);
                }
            } else if (br == 1) {
                #pragma unroll
                for (int kt = 0; kt < 12; kt += 2) {
                    ac0 = __builtin_amdgcn_mfma_f32_16x16x32_f16(
                        *(const half8*)&XH[n][kt * 32 + ao], wfb[kt], ac0, 0, 0, 0);
                    ac1 = __builtin_amdgcn_mfma_f32_16x16x32_f16(
                        *(const half8*)&XH[n][(kt + 1) * 32 + ao], wfb[kt + 1], ac1, 0, 0, 0);
                }
            } else {
                #pragma unroll
                for (int kt = 0; kt < 10; kt += 2) {
                    ac0 = __builtin_amdgcn_mfma_f32_16x16x32_f16(
                        *(const half8*)&XH[n][kt * 32 + ao], wfc[kt], ac0, 0, 0, 0);
                    ac1 = __builtin_amdgcn_mfma_f32_16x16x32_f16(
                        *(const half8*)&XH[n][(kt + 1) * 32 + ao], wfc[kt + 1], ac1, 0, 0, 0);
                }
            }
        }
        const floatx4 acc = ac0 + ac1;

        // ---- nonlinearity per-lane BEFORE gather (shortens post-shfl chain) ----
        const float bsel = (br == 0) ? ba : ((br == 1) ? bb : bc);
        float tv[4];
        #pragma unroll
        for (int r = 0; r < 4; ++r) {
            const float gv = acc[r] + bsel;
            tv[r] = (gt == 2) ? ftanh(gv) : fsig(gv);
        }
        float h2v[4];
        const int b0 = l & ~12;
        #pragma unroll
        for (int r = 0; r < 4; ++r) {
            const float vi = __shfl(tv[r], b0,      64);
            const float vf = __shfl(tv[r], b0 + 4,  64);
            const float vg = __shfl(tv[r], b0 + 8,  64);
            const float vo = __shfl(tv[r], b0 + 12, 64);
            const float c2 = vf * cst[r] + vi * vg;
            cst[r] = c2;
            h2v[r] = vo * ftanh(c2);
        }

        // ---- publish h(t) FIRST (critical path): self-tagged sc1 chunks ----
        {
            uint8_t* sb = hring + (size_t)(t & smask) * 16384 + (size_t)(8 * g + 2 * w) * 8;
            const int s0 = l & ~15;
            #pragma unroll
            for (int r = 0; r < 4; ++r) {
                const unsigned hv =
                    (unsigned)__builtin_bit_cast(unsigned short, (_Float16)h2v[r]);
                const unsigned v0 = (unsigned)__shfl((int)hv, s0,     64);
                const unsigned v1 = (unsigned)__shfl((int)hv, s0 + 1, 64);
                const unsigned v2 = (unsigned)__shfl((int)hv, s0 + 2, 64);
                const unsigned v3 = (unsigned)__shfl((int)hv, s0 + 3, 64);
                if (n == 0) {
                    u32x4 pk = { (v0 & 0xffffu) | (v1 << 16), (unsigned)t,
                                 (v2 & 0xffffu) | (v3 << 16), (unsigned)t };
                    st16_sc1(sb + (size_t)(mg * 4 + r) * 1024, pk);
                }
            }
        }

        // ---- store ys[t] fp32 (off critical path) ----
        if (gt == 0) {   // lanes with n == up hold their own h2v
            float* op = out + (size_t)t * 4096 + (size_t)(mg * 4) * 256 + unit;
            #pragma unroll
            for (int r = 0; r < 4; ++r) op[r * 256] = h2v[r];
        }
    }
}

extern "C" void kernel_launch(void* const* d_in, const int* in_sizes, int n_in,
                              void* d_out, int out_size, void* d_ws, size_t ws_size,
                              hipStream_t stream) {
    (void)in_sizes; (void)n_in; (void)out_size;
    const int smask = (ws_size >= 4 * 16384) ? 3 : 1;   // ring slots: 4 (or 2 if ws tiny)
    hipLaunchKernelGGL(lstm_kernel, dim3(NWG), dim3(256), 0, stream,
        (const float*)d_in[0], (const float*)d_in[1], (const float*)d_in[2],
        (const float*)d_in[3], (const float*)d_in[4], (const float*)d_in[5], (const float*)d_in[6],
        (const float*)d_in[7], (const float*)d_in[8], (const float*)d_in[9], (const float*)d_in[10],
        (const float*)d_in[11], (const float*)d_in[12], (const float*)d_in[13], (const float*)d_in[14],
        (float*)d_out, (uint8_t*)d_ws, smask);
}